// Round 1
// baseline (1041.161 us; speedup 1.0000x reference)
//
#include <hip/hip_runtime.h>
#include <math.h>

#define BIGF 1e10f
#define EPSF 1e-5f

// ---------------------------------------------------------------------------
// Kernel 1: conv1 7x7 stride2 pad3 (3->64) + BN + ReLU + maxpool 3x3 s2 p1
// in:  x [128,3,96,96]   out: [128,64,24,24]
// grid: 128 b * 8 octiles = 1024 blocks, 256 threads.
// Each block: 8 output channels, full 48x48 conv plane in registers
// (9 px/thread), input planes staged zero-padded in LDS, then pool in LDS.
// ---------------------------------------------------------------------------
__global__ __launch_bounds__(256) void conv1_bn_relu_pool(
    const float* __restrict__ x,
    const float* __restrict__ w,      // [64,3,7,7]
    const float* __restrict__ bg, const float* __restrict__ bb,
    const float* __restrict__ bm, const float* __restrict__ bv,
    float* __restrict__ out)          // [128,64,24,24]
{
    __shared__ float plane[102 * 102];   // padded 96x96 (pad 3), also reused for pooling
    const int b = blockIdx.x >> 3;
    const int ocBase = (blockIdx.x & 7) << 3;
    const int tid = threadIdx.x;

    float acc[9][8];
#pragma unroll
    for (int j = 0; j < 9; ++j)
#pragma unroll
        for (int t = 0; t < 8; ++t) acc[j][t] = 0.f;

    int rb[9], cb[9];
#pragma unroll
    for (int j = 0; j < 9; ++j) {
        int px = j * 256 + tid;          // 0..2303
        rb[j] = (px / 48) * 2;           // padded row base = oh*2 (+kh)
        cb[j] = (px % 48) * 2;
    }

    for (int ic = 0; ic < 3; ++ic) {
        __syncthreads();
        const float* xp = x + ((size_t)b * 3 + ic) * 9216;
        for (int pi = tid; pi < 102 * 102; pi += 256) {
            int pr = pi / 102, pc = pi % 102;
            int ih = pr - 3, iw = pc - 3;
            float v = 0.f;
            if (ih >= 0 && ih < 96 && iw >= 0 && iw < 96) v = xp[ih * 96 + iw];
            plane[pi] = v;
        }
        __syncthreads();
        const float* wp = w + (size_t)ocBase * 147 + ic * 49;
        for (int kh = 0; kh < 7; ++kh) {
            for (int kw = 0; kw < 7; ++kw) {
                float wv[8];
#pragma unroll
                for (int t = 0; t < 8; ++t) wv[t] = wp[t * 147 + kh * 7 + kw];
#pragma unroll
                for (int j = 0; j < 9; ++j) {
                    float v = plane[(rb[j] + kh) * 102 + cb[j] + kw];
#pragma unroll
                    for (int t = 0; t < 8; ++t) acc[j][t] = fmaf(v, wv[t], acc[j][t]);
                }
            }
        }
    }

    // Per-oc: BN+ReLU into LDS plane [48*48], then 3x3 s2 p1 maxpool to global.
#pragma unroll
    for (int t = 0; t < 8; ++t) {
        const int oc = ocBase + t;
        const float s = bg[oc] * rsqrtf(bv[oc] + EPSF);
        const float sh = bb[oc] - bm[oc] * s;
        __syncthreads();
#pragma unroll
        for (int j = 0; j < 9; ++j)
            plane[j * 256 + tid] = fmaxf(fmaf(acc[j][t], s, sh), 0.f);
        __syncthreads();
        float* op = out + ((size_t)b * 64 + oc) * 576;
        for (int p = tid; p < 576; p += 256) {
            int oh = p / 24, ow = p % 24;
            float m = -INFINITY;
            int ih0 = oh * 2 - 1, iw0 = ow * 2 - 1;
#pragma unroll
            for (int kh = 0; kh < 3; ++kh) {
                int ih = ih0 + kh;
                if (ih < 0 || ih >= 48) continue;
#pragma unroll
                for (int kw = 0; kw < 3; ++kw) {
                    int iw = iw0 + kw;
                    if (iw < 0 || iw >= 48) continue;
                    m = fmaxf(m, plane[ih * 48 + iw]);
                }
            }
            op[p] = m;
        }
    }
}

// ---------------------------------------------------------------------------
// Kernel 2: conv3x3 s1 p1 (64->64) + BN, MODE 0: +ReLU ; MODE 1: +res +ReLU
// grid: 128 b * 8 octiles = 1024 blocks, 576 threads (1 px each, 8 oc).
// Input channels staged 16-at-a-time in zero-padded LDS (26x26).
// ---------------------------------------------------------------------------
template<int MODE>
__global__ __launch_bounds__(576) void conv3_bn(
    const float* __restrict__ in,     // [128,64,24,24]
    const float* __restrict__ w,      // [64,64,3,3] (layer-offset applied by caller)
    const float* __restrict__ bg, const float* __restrict__ bb,
    const float* __restrict__ bm, const float* __restrict__ bv,
    const float* __restrict__ res,    // MODE==1 only
    float* __restrict__ out)
{
    __shared__ float plane[16][676];  // 16 ic, padded 26x26
    const int b = blockIdx.x >> 3;
    const int ocBase = (blockIdx.x & 7) << 3;
    const int tid = threadIdx.x;      // 0..575
    const int oh = tid / 24, ow = tid % 24;

    float acc[8];
#pragma unroll
    for (int t = 0; t < 8; ++t) acc[t] = 0.f;

    for (int c0 = 0; c0 < 64; c0 += 16) {
        __syncthreads();
        for (int li = tid; li < 16 * 676; li += 576) {
            int icL = li / 676, pi = li % 676;
            int pr = pi / 26, pc = pi % 26;
            int ih = pr - 1, iw = pc - 1;
            float v = 0.f;
            if (ih >= 0 && ih < 24 && iw >= 0 && iw < 24)
                v = in[((size_t)b * 64 + c0 + icL) * 576 + ih * 24 + iw];
            plane[icL][pi] = v;
        }
        __syncthreads();
#pragma unroll 2
        for (int icL = 0; icL < 16; ++icL) {
            const float* pp = &plane[icL][oh * 26 + ow];
            float v0 = pp[0],  v1 = pp[1],  v2 = pp[2];
            float v3 = pp[26], v4 = pp[27], v5 = pp[28];
            float v6 = pp[52], v7 = pp[53], v8 = pp[54];
            const float* wp = w + (size_t)ocBase * 576 + (c0 + icL) * 9;
#pragma unroll
            for (int t = 0; t < 8; ++t) {
                const float* wt = wp + t * 576;
                float a = acc[t];
                a = fmaf(v0, wt[0], a);
                a = fmaf(v1, wt[1], a);
                a = fmaf(v2, wt[2], a);
                a = fmaf(v3, wt[3], a);
                a = fmaf(v4, wt[4], a);
                a = fmaf(v5, wt[5], a);
                a = fmaf(v6, wt[6], a);
                a = fmaf(v7, wt[7], a);
                a = fmaf(v8, wt[8], a);
                acc[t] = a;
            }
        }
    }

#pragma unroll
    for (int t = 0; t < 8; ++t) {
        const int oc = ocBase + t;
        const float s = bg[oc] * rsqrtf(bv[oc] + EPSF);
        const float sh = bb[oc] - bm[oc] * s;
        float v = fmaf(acc[t], s, sh);
        size_t oidx = ((size_t)b * 64 + oc) * 576 + tid;
        if (MODE == 1) v = fmaxf(v + res[oidx], 0.f);
        else           v = fmaxf(v, 0.f);
        out[oidx] = v;
    }
}

// ---------------------------------------------------------------------------
// Kernel 3: FC split-K GEMM. cost[b,n] = sum_k h[b,k]*fcw[n,k]  (bias in reduce)
// M=128, N=144, K=36864. Grid (4 mtiles, 3 ntiles, 36 ksplits), 256 threads.
// Each block: 32x48 tile over a 1024-long K chunk -> partials.
// ---------------------------------------------------------------------------
#define KSPLIT 36
#define KCHUNK 1024

__global__ __launch_bounds__(256) void fc_splitk(
    const float* __restrict__ A,   // [128, 36864]
    const float* __restrict__ B,   // [144, 36864]
    float* __restrict__ part)      // [36][128*144]
{
    __shared__ float As[32][33];
    __shared__ float Bs[48][33];
    const int mBase = blockIdx.x * 32;
    const int nBase = blockIdx.y * 48;
    const int s = blockIdx.z;
    const int t = threadIdx.x;
    const int mIdx = t >> 4, nIdx = t & 15;

    float acc[2][3] = {{0.f,0.f,0.f},{0.f,0.f,0.f}};

    const int k0 = s * KCHUNK;
    for (int kk = k0; kk < k0 + KCHUNK; kk += 32) {
        __syncthreads();
#pragma unroll
        for (int i = 0; i < 4; ++i) {
            int li = t + i * 256; int r = li >> 5, c = li & 31;
            As[r][c] = A[(size_t)(mBase + r) * 36864 + kk + c];
        }
#pragma unroll
        for (int i = 0; i < 6; ++i) {
            int li = t + i * 256; int r = li >> 5, c = li & 31;
            Bs[r][c] = B[(size_t)(nBase + r) * 36864 + kk + c];
        }
        __syncthreads();
#pragma unroll
        for (int k = 0; k < 32; ++k) {
            float a0 = As[mIdx][k], a1 = As[mIdx + 16][k];
            float b0 = Bs[nIdx][k], b1 = Bs[nIdx + 16][k], b2 = Bs[nIdx + 32][k];
            acc[0][0] = fmaf(a0, b0, acc[0][0]);
            acc[0][1] = fmaf(a0, b1, acc[0][1]);
            acc[0][2] = fmaf(a0, b2, acc[0][2]);
            acc[1][0] = fmaf(a1, b0, acc[1][0]);
            acc[1][1] = fmaf(a1, b1, acc[1][1]);
            acc[1][2] = fmaf(a1, b2, acc[1][2]);
        }
    }
    float* pp = part + (size_t)s * (128 * 144);
#pragma unroll
    for (int i = 0; i < 2; ++i)
#pragma unroll
        for (int j = 0; j < 3; ++j)
            pp[(size_t)(mBase + mIdx + i * 16) * 144 + nBase + nIdx + j * 16] = acc[i][j];
}

__global__ __launch_bounds__(256) void fc_reduce(
    const float* __restrict__ part, const float* __restrict__ bias,
    float* __restrict__ costs)
{
    int idx = blockIdx.x * 256 + threadIdx.x;
    if (idx >= 128 * 144) return;
    float sum = bias[idx % 144];
    for (int s = 0; s < KSPLIT; ++s) sum += part[(size_t)s * (128 * 144) + idx];
    costs[idx] = sum;
}

// ---------------------------------------------------------------------------
// Kernel 4: per-sample Bellman-Ford (exactly 144 iters, matching the ref
// semantics incl. negative costs) + greedy backtrack (first-min argmin).
// grid: 128 blocks, 192 threads (144 active cells).
// ---------------------------------------------------------------------------
__global__ __launch_bounds__(192) void shortest_path(
    const float* __restrict__ costs, float* __restrict__ out)
{
    __shared__ float dA[144], dB[144], cs[144], mask[144];
    const int b = blockIdx.x, tid = threadIdx.x;
    if (tid < 144) {
        float c = costs[b * 144 + tid];
        cs[tid] = c;
        dA[tid] = (tid == 0) ? c : BIGF;
        mask[tid] = 0.f;
    }
    __syncthreads();
    float* cur = dA; float* nxt = dB;
    for (int it = 0; it < 144; ++it) {
        if (tid < 144) {
            int i = tid / 12, j = tid % 12;
            float up = (i > 0)  ? cur[tid - 12] : BIGF;
            float dn = (i < 11) ? cur[tid + 12] : BIGF;
            float lf = (j > 0)  ? cur[tid - 1]  : BIGF;
            float rt = (j < 11) ? cur[tid + 1]  : BIGF;
            float nb = fminf(fminf(up, dn), fminf(lf, rt));
            nxt[tid] = fminf(cur[tid], nb + cs[tid]);
        }
        __syncthreads();
        float* tp = cur; cur = nxt; nxt = tp;
    }
    if (tid == 0) {
        int i = 11, j = 11;
        const int di[4] = {-1, 1, 0, 0};
        const int dj[4] = {0, 0, -1, 1};
        for (int it = 0; it < 144; ++it) {
            mask[i * 12 + j] = 1.f;
            float vals[4];
#pragma unroll
            for (int k = 0; k < 4; ++k) {
                int ni = i + di[k], nj = j + dj[k];
                bool valid = (ni >= 0) && (ni < 12) && (nj >= 0) && (nj < 12);
                vals[k] = valid ? cur[ni * 12 + nj] : BIGF;
            }
            float best = vals[0]; int kb = 0;
#pragma unroll
            for (int k = 1; k < 4; ++k)
                if (vals[k] < best) { best = vals[k]; kb = k; }   // first-min (jnp.argmin)
            if (!(i == 0 && j == 0)) { i += di[kb]; j += dj[kb]; }
        }
    }
    __syncthreads();
    if (tid < 144) out[b * 144 + tid] = mask[tid];
}

// ---------------------------------------------------------------------------
extern "C" void kernel_launch(void* const* d_in, const int* in_sizes, int n_in,
                              void* d_out, int out_size, void* d_ws, size_t ws_size,
                              hipStream_t stream) {
    const float* x    = (const float*)d_in[0];
    const float* c1w  = (const float*)d_in[1];
    const float* bn1g = (const float*)d_in[2];
    const float* bn1b = (const float*)d_in[3];
    const float* bn1m = (const float*)d_in[4];
    const float* bn1v = (const float*)d_in[5];
    const float* blkw = (const float*)d_in[6];
    const float* blkg = (const float*)d_in[7];
    const float* blkb = (const float*)d_in[8];
    const float* blkm = (const float*)d_in[9];
    const float* blkv = (const float*)d_in[10];
    const float* fcw  = (const float*)d_in[11];
    const float* fcb  = (const float*)d_in[12];
    float* out = (float*)d_out;
    float* ws  = (float*)d_ws;

    const size_t ACT = 4718592;              // 128*64*24*24
    float* hp    = ws;                       // pooled / final hidden
    float* t1    = ws + ACT;
    float* h2    = ws + 2 * ACT;
    float* costs = ws + 3 * ACT;             // 18432
    float* part  = costs + 18432;            // 36*18432

    conv1_bn_relu_pool<<<dim3(1024), dim3(256), 0, stream>>>(
        x, c1w, bn1g, bn1b, bn1m, bn1v, hp);

    // layer1, block 0
    conv3_bn<0><<<dim3(1024), dim3(576), 0, stream>>>(
        hp, blkw + 0 * 36864, blkg + 0,   blkb + 0,   blkm + 0,   blkv + 0,   nullptr, t1);
    conv3_bn<1><<<dim3(1024), dim3(576), 0, stream>>>(
        t1, blkw + 1 * 36864, blkg + 64,  blkb + 64,  blkm + 64,  blkv + 64,  hp, h2);
    // layer1, block 1
    conv3_bn<0><<<dim3(1024), dim3(576), 0, stream>>>(
        h2, blkw + 2 * 36864, blkg + 128, blkb + 128, blkm + 128, blkv + 128, nullptr, t1);
    conv3_bn<1><<<dim3(1024), dim3(576), 0, stream>>>(
        t1, blkw + 3 * 36864, blkg + 192, blkb + 192, blkm + 192, blkv + 192, h2, hp);

    fc_splitk<<<dim3(4, 3, 36), dim3(256), 0, stream>>>(hp, fcw, part);
    fc_reduce<<<dim3(72), dim3(256), 0, stream>>>(part, fcb, costs);
    shortest_path<<<dim3(128), dim3(192), 0, stream>>>(costs, out);
}

// Round 2
// 758.674 us; speedup vs baseline: 1.3723x; 1.3723x over previous
//
#include <hip/hip_runtime.h>
#include <math.h>

#define BIGF 1e10f
#define EPSF 1e-5f

// ---------------------------------------------------------------------------
// Prepack: fold BN into conv weights + biases, repack for contiguous uniform
// (scalar) loads. Written into the `part` scratch region (dead until FC).
//   wp3 layout: [layer4][ocg8][ic64][ocL8][tap9]           (147456 floats)
//   wp1 layout: [ocg8][ic3][tap49][ocL8]                   (9408 floats)
//   b3[256], b1[64]
// ---------------------------------------------------------------------------
__global__ __launch_bounds__(256) void prepack(
    const float* __restrict__ c1w,
    const float* __restrict__ bn1g, const float* __restrict__ bn1b,
    const float* __restrict__ bn1m, const float* __restrict__ bn1v,
    const float* __restrict__ blkw,
    const float* __restrict__ blkg, const float* __restrict__ blkb,
    const float* __restrict__ blkm, const float* __restrict__ blkv,
    float* __restrict__ wp3, float* __restrict__ wp1,
    float* __restrict__ b3, float* __restrict__ b1)
{
    int idx = blockIdx.x * 256 + threadIdx.x;
    if (idx < 147456) {
        int tap = idx % 9; int r = idx / 9;
        int ocL = r % 8; r >>= 3;
        int ic  = r % 64; r >>= 6;
        int ocg = r % 8; int layer = r >> 3;
        int oc = ocg * 8 + ocL;
        float s = blkg[layer * 64 + oc] * rsqrtf(blkv[layer * 64 + oc] + EPSF);
        wp3[idx] = blkw[(((size_t)layer * 64 + oc) * 64 + ic) * 9 + tap] * s;
    }
    int j = idx - 147456;
    if (j >= 0 && j < 9408) {
        int ocL = j % 8; int r = j / 8;
        int tap = r % 49; r /= 49;
        int ic  = r % 3;  int ocg = r / 3;
        int oc = ocg * 8 + ocL;
        float s = bn1g[oc] * rsqrtf(bn1v[oc] + EPSF);
        wp1[j] = c1w[((size_t)oc * 3 + ic) * 49 + tap] * s;
    }
    int k = idx - 147456 - 9408;
    if (k >= 0 && k < 256) {
        float s = blkg[k] * rsqrtf(blkv[k] + EPSF);
        b3[k] = blkb[k] - blkm[k] * s;
    }
    int l = idx - 147456 - 9408 - 256;
    if (l >= 0 && l < 64) {
        float s = bn1g[l] * rsqrtf(bn1v[l] + EPSF);
        b1[l] = bn1b[l] - bn1m[l] * s;
    }
}

// ---------------------------------------------------------------------------
// Kernel 1: conv1 7x7 s2 p3 (3->64) + foldedBN + ReLU + maxpool 3x3 s2 p1
// 1024 blocks (ocg = bid>>7, b = bid&127 -> all 8 ocg of an image share XCD),
// 576 threads, 4 px x 8 oc per thread. Plane zeroed once (halo is all-zero).
// ---------------------------------------------------------------------------
__global__ __launch_bounds__(576) void conv1_pool(
    const float* __restrict__ x, const float* __restrict__ wp1,
    const float* __restrict__ bias, float* __restrict__ out)
{
    __shared__ float plane[102 * 102];
    const int bid = blockIdx.x;
    const int ocg = bid >> 7, b = bid & 127;
    const int tid = threadIdx.x;

    float acc[4][8];
#pragma unroll
    for (int j = 0; j < 4; ++j)
#pragma unroll
        for (int t = 0; t < 8; ++t) acc[j][t] = 0.f;

    int offp[4];
#pragma unroll
    for (int j = 0; j < 4; ++j) {
        int px = tid + 576 * j;                 // 0..2303 (48x48 conv out)
        offp[j] = (px / 48) * 2 * 102 + (px % 48) * 2;
    }

    for (int k = tid; k < 102 * 102; k += 576) plane[k] = 0.f;

    const float* xb = x + (size_t)b * 3 * 9216;
    for (int ic = 0; ic < 3; ++ic) {
        __syncthreads();
#pragma unroll
        for (int k = 0; k < 16; ++k) {
            int p = tid + 576 * k;              // 0..9215 (96x96 interior)
            plane[(p / 96 + 3) * 102 + (p % 96) + 3] = xb[ic * 9216 + p];
        }
        __syncthreads();
        const float* wq = wp1 + ((size_t)ocg * 3 + ic) * 392;
#pragma unroll 1
        for (int kh = 0; kh < 7; ++kh) {
#pragma unroll
            for (int kw = 0; kw < 7; ++kw) {
                const float* wt = wq + (kh * 7 + kw) * 8;
                float w0 = wt[0], w1 = wt[1], w2 = wt[2], w3 = wt[3];
                float w4 = wt[4], w5 = wt[5], w6 = wt[6], w7 = wt[7];
#pragma unroll
                for (int j = 0; j < 4; ++j) {
                    float v = plane[offp[j] + kh * 102 + kw];
                    acc[j][0] = fmaf(v, w0, acc[j][0]);
                    acc[j][1] = fmaf(v, w1, acc[j][1]);
                    acc[j][2] = fmaf(v, w2, acc[j][2]);
                    acc[j][3] = fmaf(v, w3, acc[j][3]);
                    acc[j][4] = fmaf(v, w4, acc[j][4]);
                    acc[j][5] = fmaf(v, w5, acc[j][5]);
                    acc[j][6] = fmaf(v, w6, acc[j][6]);
                    acc[j][7] = fmaf(v, w7, acc[j][7]);
                }
            }
        }
    }

    const int ph = tid / 24, pw = tid % 24;
    float* op = out + ((size_t)b * 64 + ocg * 8) * 576;
#pragma unroll
    for (int t = 0; t < 8; ++t) {
        float bi = bias[ocg * 8 + t];
        __syncthreads();
#pragma unroll
        for (int j = 0; j < 4; ++j)
            plane[tid + 576 * j] = fmaxf(acc[j][t] + bi, 0.f);
        __syncthreads();
        float m = -INFINITY;
        int ih0 = ph * 2 - 1, iw0 = pw * 2 - 1;
#pragma unroll
        for (int kh = 0; kh < 3; ++kh) {
            int ih = ih0 + kh;
            if (ih < 0 || ih >= 48) continue;
#pragma unroll
            for (int kw = 0; kw < 3; ++kw) {
                int iw = iw0 + kw;
                if (iw < 0 || iw >= 48) continue;
                m = fmaxf(m, plane[ih * 48 + iw]);
            }
        }
        op[t * 576 + tid] = m;
    }
}

// ---------------------------------------------------------------------------
// Kernel 2: conv3x3 s1 p1 (64->64) + foldedBN (+res) + ReLU
// 1024 blocks (ocg = bid>>7, b = bid&127), 576 threads, 1 px x 8 oc.
// Halo is all-zero: zero borders once, stage interior with coalesced loads,
// zero index arithmetic. Weights prepacked contiguous per ic (72 dwords).
// ---------------------------------------------------------------------------
template<int MODE>
__global__ __launch_bounds__(576) void conv3_bn(
    const float* __restrict__ in,       // [128,64,24,24]
    const float* __restrict__ wp,       // [8 ocg][64 ic][8 oc][9] folded
    const float* __restrict__ bias,     // [64] folded
    const float* __restrict__ res,      // MODE==1 only
    float* __restrict__ out)
{
    __shared__ float plane[16][676];    // 16 ic, padded 26x26
    const int bid = blockIdx.x;
    const int ocg = bid >> 7, b = bid & 127;
    const int tid = threadIdx.x;        // = r*24 + c
    const int ohw = (tid / 24 + 1) * 26 + (tid % 24 + 1);

    float acc[8] = {0.f, 0.f, 0.f, 0.f, 0.f, 0.f, 0.f, 0.f};

    // zero the halo once (it never changes)
    for (int k = tid; k < 16 * 100; k += 576) {
        int icL = k / 100, bi = k % 100;
        int r, c;
        if (bi < 26)      { r = 0;          c = bi; }
        else if (bi < 52) { r = 25;         c = bi - 26; }
        else if (bi < 76) { r = bi - 52 + 1; c = 0; }
        else              { r = bi - 76 + 1; c = 25; }
        plane[icL][r * 26 + c] = 0.f;
    }

    const float* inb = in + (size_t)b * (64 * 576);
    const float* wg  = wp + (size_t)ocg * (64 * 72);

    for (int c0 = 0; c0 < 64; c0 += 16) {
        __syncthreads();
#pragma unroll
        for (int icL = 0; icL < 16; ++icL)
            plane[icL][ohw] = inb[(c0 + icL) * 576 + tid];
        __syncthreads();
#pragma unroll 2
        for (int icL = 0; icL < 16; ++icL) {
            const float* pp = &plane[icL][ohw - 27];   // top-left tap
            float v0 = pp[0],  v1 = pp[1],  v2 = pp[2];
            float v3 = pp[26], v4 = pp[27], v5 = pp[28];
            float v6 = pp[52], v7 = pp[53], v8 = pp[54];
            const float* wq = wg + (c0 + icL) * 72;
#pragma unroll
            for (int t = 0; t < 8; ++t) {
                const float* wt = wq + t * 9;
                float a = acc[t];
                a = fmaf(v0, wt[0], a);
                a = fmaf(v1, wt[1], a);
                a = fmaf(v2, wt[2], a);
                a = fmaf(v3, wt[3], a);
                a = fmaf(v4, wt[4], a);
                a = fmaf(v5, wt[5], a);
                a = fmaf(v6, wt[6], a);
                a = fmaf(v7, wt[7], a);
                a = fmaf(v8, wt[8], a);
                acc[t] = a;
            }
        }
    }

#pragma unroll
    for (int t = 0; t < 8; ++t) {
        const int oc = ocg * 8 + t;
        float v = acc[t] + bias[oc];
        size_t oidx = ((size_t)b * 64 + oc) * 576 + tid;
        if (MODE == 1) v += res[oidx];
        out[oidx] = fmaxf(v, 0.f);
    }
}

// ---------------------------------------------------------------------------
// Kernel 3: FC split-K GEMM (unchanged)
// ---------------------------------------------------------------------------
#define KSPLIT 36
#define KCHUNK 1024

__global__ __launch_bounds__(256) void fc_splitk(
    const float* __restrict__ A,   // [128, 36864]
    const float* __restrict__ B,   // [144, 36864]
    float* __restrict__ part)      // [36][128*144]
{
    __shared__ float As[32][33];
    __shared__ float Bs[48][33];
    const int mBase = blockIdx.x * 32;
    const int nBase = blockIdx.y * 48;
    const int s = blockIdx.z;
    const int t = threadIdx.x;
    const int mIdx = t >> 4, nIdx = t & 15;

    float acc[2][3] = {{0.f,0.f,0.f},{0.f,0.f,0.f}};

    const int k0 = s * KCHUNK;
    for (int kk = k0; kk < k0 + KCHUNK; kk += 32) {
        __syncthreads();
#pragma unroll
        for (int i = 0; i < 4; ++i) {
            int li = t + i * 256; int r = li >> 5, c = li & 31;
            As[r][c] = A[(size_t)(mBase + r) * 36864 + kk + c];
        }
#pragma unroll
        for (int i = 0; i < 6; ++i) {
            int li = t + i * 256; int r = li >> 5, c = li & 31;
            Bs[r][c] = B[(size_t)(nBase + r) * 36864 + kk + c];
        }
        __syncthreads();
#pragma unroll
        for (int k = 0; k < 32; ++k) {
            float a0 = As[mIdx][k], a1 = As[mIdx + 16][k];
            float b0 = Bs[nIdx][k], b1 = Bs[nIdx + 16][k], b2 = Bs[nIdx + 32][k];
            acc[0][0] = fmaf(a0, b0, acc[0][0]);
            acc[0][1] = fmaf(a0, b1, acc[0][1]);
            acc[0][2] = fmaf(a0, b2, acc[0][2]);
            acc[1][0] = fmaf(a1, b0, acc[1][0]);
            acc[1][1] = fmaf(a1, b1, acc[1][1]);
            acc[1][2] = fmaf(a1, b2, acc[1][2]);
        }
    }
    float* pp = part + (size_t)s * (128 * 144);
#pragma unroll
    for (int i = 0; i < 2; ++i)
#pragma unroll
        for (int j = 0; j < 3; ++j)
            pp[(size_t)(mBase + mIdx + i * 16) * 144 + nBase + nIdx + j * 16] = acc[i][j];
}

__global__ __launch_bounds__(256) void fc_reduce(
    const float* __restrict__ part, const float* __restrict__ bias,
    float* __restrict__ costs)
{
    int idx = blockIdx.x * 256 + threadIdx.x;
    if (idx >= 128 * 144) return;
    float sum = bias[idx % 144];
    for (int s = 0; s < KSPLIT; ++s) sum += part[(size_t)s * (128 * 144) + idx];
    costs[idx] = sum;
}

// ---------------------------------------------------------------------------
// Kernel 4: Bellman-Ford (144 iters) + greedy backtrack (unchanged)
// ---------------------------------------------------------------------------
__global__ __launch_bounds__(192) void shortest_path(
    const float* __restrict__ costs, float* __restrict__ out)
{
    __shared__ float dA[144], dB[144], cs[144], mask[144];
    const int b = blockIdx.x, tid = threadIdx.x;
    if (tid < 144) {
        float c = costs[b * 144 + tid];
        cs[tid] = c;
        dA[tid] = (tid == 0) ? c : BIGF;
        mask[tid] = 0.f;
    }
    __syncthreads();
    float* cur = dA; float* nxt = dB;
    for (int it = 0; it < 144; ++it) {
        if (tid < 144) {
            int i = tid / 12, j = tid % 12;
            float up = (i > 0)  ? cur[tid - 12] : BIGF;
            float dn = (i < 11) ? cur[tid + 12] : BIGF;
            float lf = (j > 0)  ? cur[tid - 1]  : BIGF;
            float rt = (j < 11) ? cur[tid + 1]  : BIGF;
            float nb = fminf(fminf(up, dn), fminf(lf, rt));
            nxt[tid] = fminf(cur[tid], nb + cs[tid]);
        }
        __syncthreads();
        float* tp = cur; cur = nxt; nxt = tp;
    }
    if (tid == 0) {
        int i = 11, j = 11;
        const int di[4] = {-1, 1, 0, 0};
        const int dj[4] = {0, 0, -1, 1};
        for (int it = 0; it < 144; ++it) {
            mask[i * 12 + j] = 1.f;
            float vals[4];
#pragma unroll
            for (int k = 0; k < 4; ++k) {
                int ni = i + di[k], nj = j + dj[k];
                bool valid = (ni >= 0) && (ni < 12) && (nj >= 0) && (nj < 12);
                vals[k] = valid ? cur[ni * 12 + nj] : BIGF;
            }
            float best = vals[0]; int kb = 0;
#pragma unroll
            for (int k = 1; k < 4; ++k)
                if (vals[k] < best) { best = vals[k]; kb = k; }
            if (!(i == 0 && j == 0)) { i += di[kb]; j += dj[kb]; }
        }
    }
    __syncthreads();
    if (tid < 144) out[b * 144 + tid] = mask[tid];
}

// ---------------------------------------------------------------------------
extern "C" void kernel_launch(void* const* d_in, const int* in_sizes, int n_in,
                              void* d_out, int out_size, void* d_ws, size_t ws_size,
                              hipStream_t stream) {
    const float* x    = (const float*)d_in[0];
    const float* c1w  = (const float*)d_in[1];
    const float* bn1g = (const float*)d_in[2];
    const float* bn1b = (const float*)d_in[3];
    const float* bn1m = (const float*)d_in[4];
    const float* bn1v = (const float*)d_in[5];
    const float* blkw = (const float*)d_in[6];
    const float* blkg = (const float*)d_in[7];
    const float* blkb = (const float*)d_in[8];
    const float* blkm = (const float*)d_in[9];
    const float* blkv = (const float*)d_in[10];
    const float* fcw  = (const float*)d_in[11];
    const float* fcb  = (const float*)d_in[12];
    float* out = (float*)d_out;
    float* ws  = (float*)d_ws;

    const size_t ACT = 4718592;              // 128*64*24*24
    float* hp    = ws;
    float* t1    = ws + ACT;
    float* h2    = ws + 2 * ACT;
    float* costs = ws + 3 * ACT;             // 18432
    float* part  = costs + 18432;            // 36*18432 floats
    // packed weights overlap `part` (dead until FC; convs done by then)
    float* wp3 = part;                       // 147456
    float* wp1 = wp3 + 147456;               // 9408
    float* b3  = wp1 + 9408;                 // 256
    float* b1  = b3 + 256;                   // 64

    prepack<<<dim3(614), dim3(256), 0, stream>>>(
        c1w, bn1g, bn1b, bn1m, bn1v, blkw, blkg, blkb, blkm, blkv,
        wp3, wp1, b3, b1);

    conv1_pool<<<dim3(1024), dim3(576), 0, stream>>>(x, wp1, b1, hp);

    conv3_bn<0><<<dim3(1024), dim3(576), 0, stream>>>(
        hp, wp3 + 0 * 36864, b3 + 0,   nullptr, t1);
    conv3_bn<1><<<dim3(1024), dim3(576), 0, stream>>>(
        t1, wp3 + 1 * 36864, b3 + 64,  hp, h2);
    conv3_bn<0><<<dim3(1024), dim3(576), 0, stream>>>(
        h2, wp3 + 2 * 36864, b3 + 128, nullptr, t1);
    conv3_bn<1><<<dim3(1024), dim3(576), 0, stream>>>(
        t1, wp3 + 3 * 36864, b3 + 192, h2, hp);

    fc_splitk<<<dim3(4, 3, 36), dim3(256), 0, stream>>>(hp, fcw, part);
    fc_reduce<<<dim3(72), dim3(256), 0, stream>>>(part, fcb, costs);
    shortest_path<<<dim3(128), dim3(192), 0, stream>>>(costs, out);
}